// Round 4
// baseline (705.776 us; speedup 1.0000x reference)
//
#include <hip/hip_runtime.h>
#include <hip/hip_bf16.h>

// ---------------------------------------------------------------------------
// PIDMultiHeadAttention — Round 8.
// Round-7 bench died (container failed twice) — cannot distinguish infra
// flake from a GPU hang in the never-before-executed global_load_lds path.
// Round 8 = round-7 algorithm with ONLY proven instructions:
//  * staged bytes are pass-through bf16 (derivative precomputed by scan_final
//    into d_out scratch; gate scaling moved to accumulator rescale) — this is
//    the actual fix for the measured staging-VALU bottleneck (MfmaUtil 10.8%,
//    VALUBusy 42%, 2.8e7 LDS conflict cycles)
//  * staging = reg-stage: global short8 load -> contiguous ds_write_b128
//    (lane*16B linear — conflict-free); rotation swizzle carried on the
//    per-lane GLOBAL source address; reads use the rotated offset
//    (de-conflicts the old 4-way read conflict)
//  * B-operand: bf16 wire -> direct; f32 wire + big ws -> one-time cvt_w;
//    f32 wire + small ws -> f32 load + cvt_pk before LDS write
//  * global_load_lds deferred until this path's counters are in hand
// ---------------------------------------------------------------------------

#define D_MODEL 1024
#define T_SEQ   2048
#define B_SZ    2
#define M_ROWS  (B_SZ * T_SEQ)   // 4096
#define N_HEADS 16
#define D_HEAD  64

typedef unsigned short u16;
typedef unsigned int   u32;

typedef short  short8  __attribute__((ext_vector_type(8)));
typedef float  float4v __attribute__((ext_vector_type(4)));

__device__ __forceinline__ float bf2f(u16 u) {
    union { u32 i; float f; } c; c.i = ((u32)u) << 16; return c.f;
}
__device__ __forceinline__ u16 f2bf(float f) {
    union { float f; u32 i; } c; c.f = f;
    u32 i = c.i;
    i += 0x7FFFu + ((i >> 16) & 1u);   // RNE
    return (u16)(i >> 16);
}
// compiler-friendly cvt (pairs into v_cvt_pk_bf16_f32; same RNE)
__device__ __forceinline__ u16 f2bfc(float f) {
    __hip_bfloat16 h = __float2bfloat16(f);
    union { __hip_bfloat16 h; u16 u; } c; c.h = h; return c.u;
}
__device__ __forceinline__ float ldin(const void* p, int i, int fl) {
    return fl ? ((const float*)p)[i] : bf2f(((const u16*)p)[i]);
}

// ---------------------------------------------------------------------------
// 0) wire-dtype detection (proven since round 2)
// ---------------------------------------------------------------------------
__global__ void detect_kernel(const u32* __restrict__ x, int* __restrict__ flag)
{
    if (threadIdx.x == 0 && blockIdx.x == 0) {
        int good = 0;
        for (int i = 0; i < 256; ++i) {
            union { u32 u; float f; } c; c.u = x[i];
            float a = fabsf(c.f);
            if (c.f == c.f && a > 1e-8f && a < 1e4f) ++good;
        }
        *flag = (good >= 192) ? 1 : 0;
    }
}

// ---------------------------------------------------------------------------
// 1) cumulative-mean scan; scan_final also emits bf16(x) (f32 wire) and the
//    bf16 derivative into d_out scratch (dead until the final GEMM)
// ---------------------------------------------------------------------------
__global__ __launch_bounds__(256) void scan_partial(
    const void* __restrict__ x, float* __restrict__ csum,
    const int* __restrict__ flagp)
{
    int fl = *flagp;
    int tid = blockIdx.x * 256 + threadIdx.x;   // 32768 = B * 16 * D
    int b = tid >> 14;
    int c = (tid >> 10) & 15;
    int d = tid & 1023;
    int base = (b * T_SEQ + c * 128) * D_MODEL + d;
    float s = 0.f;
#pragma unroll 8
    for (int t = 0; t < 128; ++t) s += ldin(x, base + t * D_MODEL, fl);
    csum[tid] = s;
}

__global__ __launch_bounds__(256) void scan_final(
    const void* __restrict__ x, const float* __restrict__ csum,
    u16* __restrict__ integ, u16* __restrict__ ob16,
    const int* __restrict__ flagp)
{
    int fl = *flagp;
    const size_t SZ = (size_t)M_ROWS * D_MODEL;
    u16* xb_w = fl ? ob16 : nullptr;          // bf16 copy of x (f32 wire)
    u16* db_w = fl ? (ob16 + SZ) : ob16;      // bf16 derivative

    int tid = blockIdx.x * 256 + threadIdx.x;
    int b = tid >> 14;
    int c = (tid >> 10) & 15;
    int d = tid & 1023;
    float pre = 0.f;
    int cbase = (b << 14) | d;
    for (int cc = 0; cc < c; ++cc) pre += csum[cbase + (cc << 10)];
    int base = (b * T_SEQ + c * 128) * D_MODEL + d;
    float run = pre;
    int t0 = c * 128;
    float xprev = (c != 0) ? ldin(x, base - D_MODEL, fl) : 0.f;
    for (int t = 0; t < 128; ++t) {
        float xv = ldin(x, base + t * D_MODEL, fl);
        run += xv;
        integ[base + t * D_MODEL] = f2bf(run / (float)(t0 + t + 1));
        if (xb_w) xb_w[base + t * D_MODEL] = f2bf(xv);
        float dv = (t0 + t == 0) ? 0.f : (xv - xprev);
        db_w[base + t * D_MODEL] = f2bf(dv);
        xprev = xv;
    }
}

// ---------------------------------------------------------------------------
// 2) gate softmax (unchanged)
// ---------------------------------------------------------------------------
__global__ __launch_bounds__(64) void gates_kernel(
    const void* __restrict__ x,
    const void* __restrict__ qWg, const void* __restrict__ qbg,
    const void* __restrict__ kWg, const void* __restrict__ kbg,
    const void* __restrict__ vWg, const void* __restrict__ vbg,
    float* __restrict__ gq, float* __restrict__ gk, float* __restrict__ gv,
    const int* __restrict__ flagp)
{
    int fl = *flagp;
    int row = blockIdx.x;
    int l = threadIdx.x;
    int xb = row * D_MODEL;
    float p[9];
#pragma unroll
    for (int j = 0; j < 9; ++j) p[j] = 0.f;
#pragma unroll 4
    for (int i = 0; i < 16; ++i) {
        int d = l + 64 * i;
        float xv = ldin(x, xb + d, fl);
        p[0] += xv * ldin(qWg, d, fl);
        p[1] += xv * ldin(qWg, 1024 + d, fl);
        p[2] += xv * ldin(qWg, 2048 + d, fl);
        p[3] += xv * ldin(kWg, d, fl);
        p[4] += xv * ldin(kWg, 1024 + d, fl);
        p[5] += xv * ldin(kWg, 2048 + d, fl);
        p[6] += xv * ldin(vWg, d, fl);
        p[7] += xv * ldin(vWg, 1024 + d, fl);
        p[8] += xv * ldin(vWg, 2048 + d, fl);
    }
#pragma unroll
    for (int off = 32; off > 0; off >>= 1) {
#pragma unroll
        for (int j = 0; j < 9; ++j) p[j] += __shfl_down(p[j], off);
    }
    if (l == 0) {
        const void* bgs[3] = { qbg, kbg, vbg };
        float* outs[3] = { gq, gk, gv };
#pragma unroll
        for (int pr = 0; pr < 3; ++pr) {
            float a0 = p[pr * 3 + 0] + ldin(bgs[pr], 0, fl);
            float a1 = p[pr * 3 + 1] + ldin(bgs[pr], 1, fl);
            float a2 = p[pr * 3 + 2] + ldin(bgs[pr], 2, fl);
            float mx = fmaxf(a0, fmaxf(a1, a2));
            float e0 = __expf(a0 - mx), e1 = __expf(a1 - mx), e2 = __expf(a2 - mx);
            float inv = 1.f / (e0 + e1 + e2);
            outs[pr][row * 3 + 0] = e0 * inv;
            outs[pr][row * 3 + 1] = e1 * inv;
            outs[pr][row * 3 + 2] = e2 * inv;
        }
    }
}

// ---------------------------------------------------------------------------
// 2b) optional weight bf16 conversion (only if ws has room; skipped bf16 wire)
// ---------------------------------------------------------------------------
struct CvtArgs { const void* src[10]; };

__global__ __launch_bounds__(256) void cvt_w(
    CvtArgs a, u16* __restrict__ dst, const int* __restrict__ flagp)
{
    if (*flagp == 0) return;   // bf16 wire: originals used directly
    int m = blockIdx.y;
    const float* s = (const float*)a.src[m];
    u16* d = dst + ((size_t)m << 20);
    int i = (blockIdx.x * 256 + threadIdx.x) * 8;
    float4 v0 = *(const float4*)(s + i);
    float4 v1 = *(const float4*)(s + i + 4);
    ushort4 o0, o1;
    o0.x = f2bfc(v0.x); o0.y = f2bfc(v0.y); o0.z = f2bfc(v0.z); o0.w = f2bfc(v0.w);
    o1.x = f2bfc(v1.x); o1.y = f2bfc(v1.y); o1.z = f2bfc(v1.z); o1.w = f2bfc(v1.w);
    *(ushort4*)(d + i) = o0;
    *(ushort4*)(d + i + 4) = o1;
}

// ---------------------------------------------------------------------------
// 3) FAST MFMA GEMM, 128x128x32 tiles, double-buffered, reg-staged.
//    LDS layout (per 16-row group of 512 u16): slot (q=0..3, r'=0..15) at
//    q*128 + r'*8 holds row (r'-q)&15, k-chunk q. Writes: lane l stores its
//    16B at la + l*8 u16 (wave-contiguous 1KiB — conflict-free); the row
//    rotation is carried on the per-lane GLOBAL source address. Reads use
//    ro = quad*128 + ((lane15+quad)&15)*8 — rotated, conflict-free.
//    A is always bf16 (xb/Ib/db or AO). B: bf16 wire -> direct; f32+wb ->
//    converted cache; f32 no-wb -> f32 loads + cvt_pk before the LDS write.
//    MODE 0: K=3072 segs {xb@Wp, Ib@Wi, db@Wd}; gate scaling as accumulator
//            rescale (g0/g1 at it=32, g1/g2 at it=64), epilogue *g2.
//    MODE 1: K=1024, +bias, wire-dtype store.
// ---------------------------------------------------------------------------
struct FArgs {
    const void* W[3][3];
    const float* G[3];
    u16* C[3];
};

template<int MODE>
__global__ __launch_bounds__(256, 3) void fast_gemm(
    const void* __restrict__ Xsrc, const u16* __restrict__ xbp,
    const u16* __restrict__ Ib, FArgs args,
    const void* __restrict__ bias, void* __restrict__ outp,
    const int* __restrict__ flagp, const u16* __restrict__ wb, int Ktot)
{
    int fl = *flagp;
    const size_t SZc = (size_t)M_ROWS * D_MODEL;

    __shared__ __align__(16) u16 As[2 * 4096];
    __shared__ __align__(16) u16 Bs[2 * 4096];

    int tid = threadIdx.x;
    int l = tid & 63, w = tid >> 6;
    int wm = w >> 1, wn = w & 1;
    int lane15 = l & 15, quad = l >> 4;
    int m0 = blockIdx.x * 128, n0 = blockIdx.y * 128;   // m-major grid
    int z = blockIdx.z;

    const void *W0z, *W1z = nullptr, *W2z = nullptr;
    const float* G = nullptr;
    u16* Chead = nullptr;
    if (MODE == 0) {
        W0z = args.W[z][0]; W1z = args.W[z][1]; W2z = args.W[z][2];
        G = args.G[z]; Chead = args.C[z];
    } else {
        W0z = args.W[0][0];
    }
    const u16 *wq0 = nullptr, *wq1 = nullptr, *wq2 = nullptr;
    if (wb != nullptr) {
        size_t base = (MODE == 0) ? ((size_t)(z * 3) << 20) : ((size_t)9 << 20);
        wq0 = wb + base; wq1 = wq0 + (1u << 20); wq2 = wq1 + (1u << 20);
    }

    // staging geometry: wave w owns row-groups j0=2w, j0+1; lane l fills slot
    // (q=l>>4, r'=l&15) which holds row (r'-q)&15, k-chunk q.
    int j0 = w * 2;
    int q_s = l >> 4;
    int ri = ((l & 15) - q_s) & 15;
    int colo = q_s * 8;

    int mrow0 = m0 + j0 * 16 + ri;
    int nrow0 = n0 + j0 * 16 + ri;
    size_t aofs = (size_t)mrow0 * 1024 + colo;
    size_t nofs = (size_t)nrow0 * 1024 + colo;

    const u16* Xb = (MODE == 0) ? (fl ? xbp : (const u16*)Xsrc)
                                : (const u16*)Xsrc;
    const u16* pA0 = Xb + aofs;
    const u16 *pI0 = nullptr, *pD0 = nullptr;
    if (MODE == 0) {
        const u16* Db = fl ? (xbp + SZc) : xbp;
        pI0 = Ib + aofs;
        pD0 = Db + aofs;
    }

    bool bf16B = (fl == 0) || (wb != nullptr);

    // in-flight staged data (registers)
    short8 rA0, rA1, rB0, rB1;
    float4 bv0, bv1, bv2, bv3;

    auto loadA = [&](int it) {
        int kl  = (MODE == 0) ? ((it & 31) << 5) : (it << 5);
        int seg = (MODE == 0) ? (it >> 5) : 0;
        const u16* a = (MODE == 1 || seg == 0) ? pA0 : (seg == 1 ? pI0 : pD0);
        rA0 = *(const short8*)(a + kl);
        rA1 = *(const short8*)(a + kl + 16 * 1024);
    };
    auto loadB = [&](int it) {
        int kl  = (MODE == 0) ? ((it & 31) << 5) : (it << 5);
        int seg = (MODE == 0) ? (it >> 5) : 0;
        if (bf16B) {
            const u16* b;
            if (fl == 0) {
                const void* Wm = (MODE == 1 || seg == 0) ? W0z
                                 : (seg == 1 ? W1z : W2z);
                b = (const u16*)Wm + nofs;
            } else {
                b = ((MODE == 1 || seg == 0) ? wq0
                     : (seg == 1 ? wq1 : wq2)) + nofs;
            }
            rB0 = *(const short8*)(b + kl);
            rB1 = *(const short8*)(b + kl + 16 * 1024);
        } else {
            const float* bw = (const float*)((MODE == 1 || seg == 0) ? W0z
                                             : (seg == 1 ? W1z : W2z));
            const float* s0 = bw + nofs + kl;
            bv0 = *(const float4*)s0;
            bv1 = *(const float4*)(s0 + 4);
            const float* s1 = s0 + 16 * 1024;
            bv2 = *(const float4*)s1;
            bv3 = *(const float4*)(s1 + 4);
        }
    };
    auto writeAB = [&](int buf) {
        u16* la = As + buf * 4096 + j0 * 512 + l * 8;
        *(short8*)la = rA0;
        *(short8*)(la + 512) = rA1;
        u16* lb = Bs + buf * 4096 + j0 * 512 + l * 8;
        if (bf16B) {
            *(short8*)lb = rB0;
            *(short8*)(lb + 512) = rB1;
        } else {
            short8 p0, p1;
            p0[0] = (short)f2bfc(bv0.x); p0[1] = (short)f2bfc(bv0.y);
            p0[2] = (short)f2bfc(bv0.z); p0[3] = (short)f2bfc(bv0.w);
            p0[4] = (short)f2bfc(bv1.x); p0[5] = (short)f2bfc(bv1.y);
            p0[6] = (short)f2bfc(bv1.z); p0[7] = (short)f2bfc(bv1.w);
            p1[0] = (short)f2bfc(bv2.x); p1[1] = (short)f2bfc(bv2.y);
            p1[2] = (short)f2bfc(bv2.z); p1[3] = (short)f2bfc(bv2.w);
            p1[4] = (short)f2bfc(bv3.x); p1[5] = (short)f2bfc(bv3.y);
            p1[6] = (short)f2bfc(bv3.z); p1[7] = (short)f2bfc(bv3.w);
            *(short8*)lb = p0;
            *(short8*)(lb + 512) = p1;
        }
    };

    float4v acc[4][4];
#pragma unroll
    for (int i = 0; i < 4; ++i)
#pragma unroll
        for (int j = 0; j < 4; ++j)
#pragma unroll
            for (int r = 0; r < 4; ++r) acc[i][j][r] = 0.f;

    int nIt = Ktot >> 5;
    loadA(0); loadB(0);
    writeAB(0);

    // rotated within-group read offset (u16 units)
    int ro = quad * 128 + (((lane15 + quad) & 15) << 3);

    for (int it = 0; it < nIt; ++it) {
        __syncthreads();
        int cur = it & 1;
        if (it + 1 < nIt) { loadA(it + 1); loadB(it + 1); }

        if (MODE == 0 && (it == 32 || it == 64)) {
            int s = it >> 5;        // 1 or 2
#pragma unroll
            for (int ms = 0; ms < 4; ++ms) {
#pragma unroll
                for (int r = 0; r < 4; ++r) {
                    int row = m0 + wm * 64 + ms * 16 + quad * 4 + r;
                    float f = G[row * 3 + (s - 1)] / G[row * 3 + s];
#pragma unroll
                    for (int ns = 0; ns < 4; ++ns) acc[ms][ns][r] *= f;
                }
            }
        }

        short8 af[4], bfr[4];
#pragma unroll
        for (int ms = 0; ms < 4; ++ms)
            af[ms] = *(const short8*)&As[cur * 4096 + (wm * 4 + ms) * 512 + ro];
#pragma unroll
        for (int ns = 0; ns < 4; ++ns)
            bfr[ns] = *(const short8*)&Bs[cur * 4096 + (wn * 4 + ns) * 512 + ro];
#pragma unroll
        for (int ms = 0; ms < 4; ++ms)
#pragma unroll
            for (int ns = 0; ns < 4; ++ns)
                acc[ms][ns] = __builtin_amdgcn_mfma_f32_16x16x32_bf16(
                    af[ms], bfr[ns], acc[ms][ns], 0, 0, 0);

        if (it + 1 < nIt) writeAB(cur ^ 1);   // store after MFMA (latency hide)
    }

    // ---- epilogue ----
#pragma unroll
    for (int ms = 0; ms < 4; ++ms) {
#pragma unroll
        for (int r = 0; r < 4; ++r) {
            int m = m0 + wm * 64 + ms * 16 + quad * 4 + r;
            float fs = 1.f;
            if (MODE == 0) fs = G[m * 3 + 2];   // final gate
#pragma unroll
            for (int ns = 0; ns < 4; ++ns) {
                int n = n0 + wn * 64 + ns * 16 + lane15;
                float vv = acc[ms][ns][r];
                if (MODE == 0) {
                    vv *= fs;
                    int b = m >> 11, t = m & (T_SEQ - 1);
                    int h = n >> 6,  d = n & 63;
                    Chead[(((b << 4) + h) * T_SEQ + t) * 64 + d] = f2bf(vv);
                } else {
                    vv += ldin(bias, n, fl);
                    if (fl) ((float*)outp)[(size_t)m * 1024 + n] = vv;
                    else    ((u16*)outp)[(size_t)m * 1024 + n] = f2bf(vv);
                }
            }
        }
    }
}

// ---------------------------------------------------------------------------
// 4) MFMA flash attention (unchanged — proven, ~140 us)
// ---------------------------------------------------------------------------
__global__ __launch_bounds__(256) void attn_mfma(
    const u16* __restrict__ Qh, const u16* __restrict__ Kh,
    const u16* __restrict__ Vh, u16* __restrict__ AO)
{
    int bx = blockIdx.x;          // 1024 = B*H*(T/64)
    int qt = bx & 31;
    int bh = bx >> 5;             // 0..31
    int h  = bh & 15;
    int b  = bh >> 4;
    int tid = threadIdx.x;
    int l   = tid & 63;
    int w   = tid >> 6;
    int lane15 = l & 15;
    int quad   = l >> 4;

    __shared__ __align__(16) u16 Ks[64 * 72];
    __shared__ __align__(16) u16 Vt[64 * 72];   // transposed: [d][t_local]
    __shared__ __align__(16) u16 Ps[4 * 16 * 72];

    const u16* Qb = Qh + bh * (T_SEQ * 64);
    const u16* Kb = Kh + bh * (T_SEQ * 64);
    const u16* Vb = Vh + bh * (T_SEQ * 64);

    int qrow = qt * 64 + w * 16 + lane15;
    short8 qf[2];
#pragma unroll
    for (int ks = 0; ks < 2; ++ks)
        qf[ks] = *(const short8*)&Qb[qrow * 64 + ks * 32 + quad * 8];

    float4v oacc[4];
#pragma unroll
    for (int ds = 0; ds < 4; ++ds)
#pragma unroll
        for (int r = 0; r < 4; ++r) oacc[ds][r] = 0.f;
    float mrun[4], lrun[4];
#pragma unroll
    for (int r = 0; r < 4; ++r) { mrun[r] = -1e30f; lrun[r] = 0.f; }

    int srow = tid >> 2;
    int sdc  = (tid & 3) * 16;

    for (int kt = 0; kt <= qt; ++kt) {
        {
            const u16* kp = &Kb[(kt * 64 + srow) * 64 + sdc];
            ushort4 a = *(const ushort4*)kp;
            ushort4 c = *(const ushort4*)(kp + 4);
            ushort4 d2 = *(const ushort4*)(kp + 8);
            ushort4 e = *(const ushort4*)(kp + 12);
            short8 p0, p1;
            p0[0]=a.x; p0[1]=a.y; p0[2]=a.z; p0[3]=a.w;
            p0[4]=c.x; p0[5]=c.y; p0[6]=c.z; p0[7]=c.w;
            p1[0]=d2.x; p1[1]=d2.y; p1[2]=d2.z; p1[3]=d2.w;
            p1[4]=e.x; p1[5]=e.y; p1[6]=e.z; p1[7]=e.w;
            *(short8*)&Ks[srow * 72 + sdc] = p0;
            *(short8*)&Ks[srow * 72 + sdc + 8] = p1;

            const u16* vp = &Vb[(kt * 64 + srow) * 64 + sdc];
            u16 vv[16];
            *(ushort4*)&vv[0]  = *(const ushort4*)vp;
            *(ushort4*)&vv[4]  = *(const ushort4*)(vp + 4);
            *(ushort4*)&vv[8]  = *(const ushort4*)(vp + 8);
            *(ushort4*)&vv[12] = *(const ushort4*)(vp + 12);
#pragma unroll
            for (int e2 = 0; e2 < 16; ++e2)
                Vt[(sdc + e2) * 72 + srow] = vv[e2];
        }
        __syncthreads();

        float4v sacc[4];
#pragma unroll
        for (int ns = 0; ns < 4; ++ns)
#pragma unroll
            for (int r = 0; r < 4; ++r) sacc[ns][r] = 0.f;
#pragma unroll
        for (int ks = 0; ks < 2; ++ks) {
#pragma unroll
            for (int ns = 0; ns < 4; ++ns) {
                short8 bfk = *(const short8*)&Ks[(ns * 16 + lane15) * 72 + ks * 32 + quad * 8];
                sacc[ns] = __builtin_amdgcn_mfma_f32_16x16x32_bf16(
                    qf[ks], bfk, sacc[ns], 0, 0, 0);
            }
        }

        int qg0 = qt * 64 + w * 16 + quad * 4;
#pragma unroll
        for (int ns = 0; ns < 4; ++ns) {
            int kg = kt * 64 + ns * 16 + lane15;
#pragma unroll
            for (int r = 0; r < 4; ++r) {
                float s = sacc[ns][r] * 0.125f;
                sacc[ns][r] = (kg > qg0 + r) ? -1e30f : s;
            }
        }
#pragma unroll
        for (int r = 0; r < 4; ++r) {
            float mx = fmaxf(fmaxf(sacc[0][r], sacc[1][r]),
                             fmaxf(sacc[2][r], sacc[3][r]));
#pragma unroll
            for (int m2 = 1; m2 < 16; m2 <<= 1)
                mx = fmaxf(mx, __shfl_xor(mx, m2, 64));
            float mnew = fmaxf(mrun[r], mx);
            float al = __expf(mrun[r] - mnew);
            float rs = 0.f;
#pragma unroll
            for (int ns = 0; ns < 4; ++ns) {
                float p = __expf(sacc[ns][r] - mnew);
                sacc[ns][r] = p;
                rs += p;
            }
#pragma unroll
            for (int m2 = 1; m2 < 16; m2 <<= 1)
                rs += __shfl_xor(rs, m2, 64);
            lrun[r] = lrun[r] * al + rs;
            mrun[r] = mnew;
#pragma unroll
            for (int ds = 0; ds < 4; ++ds) oacc[ds][r] *= al;
        }

        u16* Pw = &Ps[w * 16 * 72];
#pragma unroll
        for (int ns = 0; ns < 4; ++ns)
#pragma unroll
            for (int r = 0; r < 4; ++r)
                Pw[(quad * 4 + r) * 72 + ns * 16 + lane15] = f2bf(sacc[ns][r]);

#pragma unroll
        for (int ks = 0; ks < 2; ++ks) {
            short8 afp = *(const short8*)&Pw[lane15 * 72 + ks * 32 + quad * 8];
#pragma unroll
            for (int ds = 0; ds < 4; ++ds) {
                short8 bfv = *(const short8*)&Vt[(ds * 16 + lane15) * 72 + ks * 32 + quad * 8];
                oacc[ds] = __builtin_amdgcn_mfma_f32_16x16x32_bf16(
                    afp, bfv, oacc[ds], 0, 0, 0);
            }
        }
        __syncthreads();
    }

#pragma unroll
    for (int r = 0; r < 4; ++r) {
        float inv = 1.f / lrun[r];
        int t = qt * 64 + w * 16 + quad * 4 + r;
        int orow = (b * T_SEQ + t) * 1024 + h * 64;
#pragma unroll
        for (int ds = 0; ds < 4; ++ds)
            AO[orow + ds * 16 + lane15] = f2bf(oacc[ds][r] * inv);
    }
}

// ---------------------------------------------------------------------------
extern "C" void kernel_launch(void* const* d_in, const int* in_sizes, int n_in,
                              void* d_out, int out_size, void* d_ws, size_t ws_size,
                              hipStream_t stream)
{
    const void* x   = d_in[0];
    const void* qWp = d_in[1];
    const void* qWi = d_in[2];
    const void* qWd = d_in[3];
    const void* qWg = d_in[4];
    const void* qbg = d_in[5];
    const void* kWp = d_in[6];
    const void* kWi = d_in[7];
    const void* kWd = d_in[8];
    const void* kWg = d_in[9];
    const void* kbg = d_in[10];
    const void* vWp = d_in[11];
    const void* vWi = d_in[12];
    const void* vWd = d_in[13];
    const void* vWg = d_in[14];
    const void* vbg = d_in[15];
    const void* oW  = d_in[16];
    const void* ob  = d_in[17];

    const size_t SZ = (size_t)M_ROWS * D_MODEL;   // 4,194,304 elems

    // ws layout (base 33 MiB — proven by rounds 0-2):
    int*   flag = (int*)d_ws;
    float* fws  = (float*)d_ws;
    float* csum = fws + 64;
    float* gq   = csum + 32768;
    float* gk   = gq + 3 * M_ROWS;
    float* gv   = gk + 3 * M_ROWS;
    u16* Ib = (u16*)((char*)d_ws + (1u << 20));
    u16* AO = Ib;                  // alias, disjoint in time
    u16* Qh = Ib + SZ;
    u16* Kh = Qh + SZ;
    u16* Vh = Kh + SZ;

    // bonus tier: bf16 weight cache (only if ws actually has the room)
    const size_t NEED_FULL = (size_t)(1u << 20) + 4 * SZ * 2 + ((size_t)10 << 21);
    u16* wb = (ws_size >= NEED_FULL) ? (Vh + SZ) : nullptr;

    detect_kernel<<<1, 64, 0, stream>>>((const u32*)x, flag);
    scan_partial<<<128, 256, 0, stream>>>(x, csum, flag);
    scan_final<<<128, 256, 0, stream>>>(x, csum, Ib, (u16*)d_out, flag);
    gates_kernel<<<M_ROWS, 64, 0, stream>>>(x, qWg, qbg, kWg, kbg, vWg, vbg,
                                            gq, gk, gv, flag);
    if (wb) {
        CvtArgs ca;
        ca.src[0] = qWp; ca.src[1] = qWi; ca.src[2] = qWd;
        ca.src[3] = kWp; ca.src[4] = kWi; ca.src[5] = kWd;
        ca.src[6] = vWp; ca.src[7] = vWi; ca.src[8] = vWd;
        ca.src[9] = oW;
        cvt_w<<<dim3(512, 10), 256, 0, stream>>>(ca, wb, flag);
    }

    FArgs fa;
    fa.W[0][0] = qWp; fa.W[0][1] = qWi; fa.W[0][2] = qWd;
    fa.W[1][0] = kWp; fa.W[1][1] = kWi; fa.W[1][2] = kWd;
    fa.W[2][0] = vWp; fa.W[2][1] = vWi; fa.W[2][2] = vWd;
    fa.G[0] = gq; fa.G[1] = gk; fa.G[2] = gv;
    fa.C[0] = Qh; fa.C[1] = Kh; fa.C[2] = Vh;

    fast_gemm<0><<<dim3(32, 8, 3), 256, 0, stream>>>(
        x, (const u16*)d_out, Ib, fa, nullptr, nullptr, flag, wb, 3072);

    attn_mfma<<<B_SZ * N_HEADS * (T_SEQ / 64), 256, 0, stream>>>(Qh, Kh, Vh, AO);

    FArgs fo = {};
    fo.W[0][0] = oW;
    fast_gemm<1><<<dim3(32, 8, 1), 256, 0, stream>>>(
        AO, AO, nullptr, fo, ob, d_out, flag, wb, 1024);
}